// Round 14
// baseline (13.528 us; speedup 1.0000x reference)
//
#include <hip/hip_runtime.h>
#include <hip/hip_bf16.h>

#define T_LEN  4096
#define CMAX   575               // max lag: band 512 + 63
#define ESTR   728               // per-copy stride (covers read idx <= 702)
#define ROUNDS 9                 // 9 rounds x 8 lags x 8 waves = 576 lags
#define BANDW  640               // A-band cols per tile: [t0-512, t0+128)

typedef __attribute__((ext_vector_type(8))) short short8;
typedef __attribute__((ext_vector_type(4))) float f32x4;

static __device__ __forceinline__ unsigned short f2bf(float f) {
  __hip_bfloat16 hh = __float2bfloat16(f);
  return *reinterpret_cast<unsigned short*>(&hh);
}

template <int CTRL>
static __device__ __forceinline__ float dppmov(float x) {
  return __int_as_float(__builtin_amdgcn_update_dpp(
      0, __float_as_int(x), CTRL, 0xF, 0xF, true));
}

#define CVT8(dst, va, vb) {                                                       \
    short8 _v;                                                                    \
    _v[0] = (short)f2bf((va).x); _v[1] = (short)f2bf((va).y);                     \
    _v[2] = (short)f2bf((va).z); _v[3] = (short)f2bf((va).w);                     \
    _v[4] = (short)f2bf((vb).x); _v[5] = (short)f2bf((vb).y);                     \
    _v[6] = (short)f2bf((vb).z); _v[7] = (short)f2bf((vb).w);                     \
    *reinterpret_cast<short8*>(dst) = _v; }

// lgkm-only barrier: drains LDS ops but lets global loads stay in flight
#define LBAR() { asm volatile("s_waitcnt lgkmcnt(0)" ::: "memory");               \
                 __builtin_amdgcn_s_barrier(); }

// Single launch, 2 barriers total.
// Stage the FULL 64x640 A-band (80 KB bf16) + E8 rev-k copies (11.4 KB) once;
// then all 8 waves run a barrier-free fully-unrolled K=640 MFMA loop.
__global__ __launch_bounds__(512, 2) void ssm_one(
    const float* __restrict__ u, const float* __restrict__ rho,
    const float* __restrict__ theta, const float* __restrict__ br,
    const float* __restrict__ bi, const float* __restrict__ cr,
    const float* __restrict__ ci, float* __restrict__ out) {
  __shared__ __align__(16) unsigned short Au[64 * BANDW];  // 80 KB band
  __shared__ __align__(16) unsigned short E8[8 * ESTR];    // 11.4 KB rev-k copies

  const int tid = threadIdx.x;
  const int lane = tid & 63;
  const int w = tid >> 6;                 // 0..7
  const int q = w >> 1, h = w & 1;        // row-quarter, col-half

  const int bid = blockIdx.x;             // 256 % 8 == 0 -> bijective XCD swizzle
  const int swz = (bid & 7) * 32 + (bid >> 3);
  const int t0 = (swz & 63) * 64;
  const int b0 = (swz >> 6) * 64;

  const int lrow = lane >> 4, lc16 = lane & 15;
  const float4 z4 = make_float4(0.f, 0.f, 0.f, 0.f);
  float4 av[5][2];

  // chunk c (0..5119): row = c/80, col8 = c%80; global col = t0-512+col8*8
#define LOADB(base) { _Pragma("unroll") for (int i_ = 0; i_ < 5; ++i_) {          \
    const int c_ = tid + 512 * ((base) + i_);                                     \
    const int row_ = c_ / 80, c80_ = c_ - row_ * 80;                              \
    const int gc_ = t0 - 512 + c80_ * 8;                                          \
    if ((unsigned)gc_ < 4096u) {                                                  \
      const float* p_ = u + (size_t)(b0 + row_) * T_LEN + gc_;                    \
      av[i_][0] = *reinterpret_cast<const float4*>(p_);                           \
      av[i_][1] = *reinterpret_cast<const float4*>(p_ + 4);                       \
    } else { av[i_][0] = z4; av[i_][1] = z4; } } }

#define WRITEB(base) { _Pragma("unroll") for (int i_ = 0; i_ < 5; ++i_) {         \
    const int c_ = tid + 512 * ((base) + i_);                                     \
    const int row_ = c_ / 80, c80_ = c_ - row_ * 80;                              \
    const int pe_ = (c80_ * 8) ^ ((row_ & 7) << 3);                               \
    CVT8(&Au[row_ * BANDW + pe_], av[i_][0], av[i_][1]); } }

  LOADB(0);                               // first-touch misses hide under d-eval

  // ---- zero E8 (y in (575, 702] must read 0) ----
  {
    const short8 z8 = {};
    for (int c = tid; c < ESTR; c += 512)
      *reinterpret_cast<short8*>(&E8[c * 8]) = z8;
  }

  // ---- per-mode params (lane = mode), lambda powers 0..8 ----
  const float rh = rho[lane], th = theta[lane];
  const float lr2 = -1.4426950408f * log1pf(expf(rh));       // log2 r
  const float rr_ = exp2f(lr2);
  const float lre = rr_ * __cosf(th), lim = rr_ * __sinf(th);
  const float brv = br[lane], biv = bi[lane];
  const float crv = cr[lane], civ = ci[lane];
  const float wre = crv * brv + civ * biv;                   // conj(c)*b
  const float wim = crv * biv - civ * brv;

  float Lr[9], Li[9];
  Lr[0] = 1.f; Li[0] = 0.f;
#pragma unroll
  for (int i = 1; i <= 8; ++i) {
    Lr[i] = Lr[i - 1] * lre - Li[i - 1] * lim;
    Li[i] = Lr[i - 1] * lim + Li[i - 1] * lre;
  }

  // g = conj(c)b * lam^(72w): wave w owns lags 72w .. 72w+71
  const float d0f = (float)(8 * ROUNDS * w);
  const float rd0 = exp2f(d0f * lr2);
  float f0 = d0f * (th * 0.15915494309f);
  f0 -= floorf(f0);
  const float a0 = 6.2831853072f * f0;
  const float c0 = __cosf(a0), s0 = __sinf(a0);
  float gr = rd0 * (wre * c0 - wim * s0);
  float gi = rd0 * (wre * s0 + wim * c0);

  const bool l0 = lane & 1, l1 = lane & 2, l3 = lane & 8;
  const int sig = ((lane & 1) << 2) | (lane & 2) | ((lane >> 3) & 1);
  const int cc  = ((lane >> 2) & 1) | ((lane >> 3) & 2) | ((lane >> 3) & 4);

  LBAR();                                 // E8 zeros complete (barrier 1 of 2)

  // ---- d-eval (r13-validated): DPP split-streams + shfl_xor reduce ----
#define ROUND(rnd) {                                                              \
    float v[8];                                                                   \
    _Pragma("unroll") for (int i2 = 0; i2 < 8; ++i2)                              \
      v[i2] = gr * Lr[i2] - gi * Li[i2];                     /* Re(g*lam^i2) */   \
    { const float ngr = gr * Lr[8] - gi * Li[8];                                  \
      const float ngi = gr * Li[8] + gi * Lr[8];                                  \
      gr = ngr; gi = ngi; }                                                       \
    float s4[4];                                                                  \
    _Pragma("unroll") for (int i = 0; i < 4; ++i) {                               \
      const float t_ = l0 ? v[i + 4] : v[i];                                      \
      const float u2 = l0 ? v[i] : v[i + 4];                                      \
      s4[i] = t_ + dppmov<0xB1>(u2); }                                            \
    float s2[2];                                                                  \
    _Pragma("unroll") for (int i = 0; i < 2; ++i) {                               \
      const float t_ = l1 ? s4[i + 2] : s4[i];                                    \
      const float u2 = l1 ? s4[i] : s4[i + 2];                                    \
      s2[i] = t_ + dppmov<0x4E>(u2); }                                            \
    float y_;                                                                     \
    { const float t_ = l3 ? s2[1] : s2[0];                                        \
      const float u2 = l3 ? s2[0] : s2[1];                                        \
      y_ = t_ + dppmov<0x128>(u2); }                                              \
    y_ += __shfl_xor(y_, 4);                                                      \
    y_ += __shfl_xor(y_, 16);                                                     \
    y_ += __shfl_xor(y_, 32);                                                     \
    const int d_ = 72 * w + 8 * (rnd) + sig;                                      \
    const int yy = CMAX - d_;                                                     \
    if (yy >= cc) E8[cc * ESTR + (yy - cc)] = f2bf(y_); }

  ROUND(0); ROUND(1); ROUND(2); ROUND(3);
  WRITEB(0);                              // batch-0 vmcnt drained by CVT use
  LOADB(5);
  ROUND(4); ROUND(5); ROUND(6); ROUND(7); ROUND(8);
  WRITEB(5);

  LBAR();                                 // Au + E8 fully visible (barrier 2 of 2)

  // ---- barrier-free GEMM: wave = (q, h); K = 640, fully unrolled ----
  f32x4 acc[2] = {};
  const int rowA = q * 16 + lc16;
  const int abase = rowA * BANDW;
  const int aswz = (rowA & 7) << 3;
  const int tc0 = h * 32 + lc16;          // fn=1 col = tc0+16 (same &7)
  const int pB = 7 - (tc0 & 7);
  const int bcom = pB * ESTR - pB + lrow * 8 + 63;
  const int bb0 = bcom - tc0;
  const int bb1 = bcom - tc0 - 16;

#pragma unroll
  for (int ks = 0; ks < 20; ++ks) {
    const short8 af = *reinterpret_cast<const short8*>(
        &Au[abase + ((ks * 32 + lrow * 8) ^ aswz)]);
    const short8 bf0 = *reinterpret_cast<const short8*>(&E8[bb0 + ks * 32]);
    const short8 bf1 = *reinterpret_cast<const short8*>(&E8[bb1 + ks * 32]);
    acc[0] = __builtin_amdgcn_mfma_f32_16x16x32_bf16(af, bf0, acc[0], 0, 0, 0);
    acc[1] = __builtin_amdgcn_mfma_f32_16x16x32_bf16(af, bf1, acc[1], 0, 0, 0);
  }

  // ---- epilogue ----
#pragma unroll
  for (int fn = 0; fn < 2; ++fn)
#pragma unroll
    for (int rg = 0; rg < 4; ++rg)
      out[(size_t)(b0 + q * 16 + lrow * 4 + rg) * T_LEN +
          t0 + h * 32 + fn * 16 + lc16] = acc[fn][rg];
#undef LOADB
#undef WRITEB
#undef ROUND
}

extern "C" void kernel_launch(void* const* d_in, const int* in_sizes, int n_in,
                              void* d_out, int out_size, void* d_ws, size_t ws_size,
                              hipStream_t stream) {
  const float* u     = (const float*)d_in[0];
  const float* rho   = (const float*)d_in[1];
  const float* theta = (const float*)d_in[2];
  const float* br    = (const float*)d_in[3];
  const float* bi    = (const float*)d_in[4];
  const float* cr    = (const float*)d_in[5];
  const float* ci    = (const float*)d_in[6];
  float* out = (float*)d_out;

  ssm_one<<<256, 512, 0, stream>>>(u, rho, theta, br, bi, cr, ci, out);
}

// Round 15
// 12.244 us; speedup vs baseline: 1.1048x; 1.1048x over previous
//
#include <hip/hip_runtime.h>
#include <hip/hip_bf16.h>

#define T_LEN  4096
#define NLAG   5
#define CMAX   575               // max lag covered
#define ESTR   728               // per-copy stride (bf16 elems)
#define ROUNDS 9                 // 9 rounds x 8 lags = 72 lags per consumer wave

typedef __attribute__((ext_vector_type(8))) short short8;
typedef __attribute__((ext_vector_type(4))) float f32x4;

static __device__ __forceinline__ unsigned short f2bf(float f) {
  __hip_bfloat16 h = __float2bfloat16(f);
  return *reinterpret_cast<unsigned short*>(&h);
}

template <int CTRL>
static __device__ __forceinline__ float dppmov(float x) {
  return __int_as_float(__builtin_amdgcn_update_dpp(
      0, __float_as_int(x), CTRL, 0xF, 0xF, true));
}

#define CVT8(dst, va, vb) {                                                       \
    short8 _v;                                                                    \
    _v[0] = (short)f2bf((va).x); _v[1] = (short)f2bf((va).y);                     \
    _v[2] = (short)f2bf((va).z); _v[3] = (short)f2bf((va).w);                     \
    _v[4] = (short)f2bf((vb).x); _v[5] = (short)f2bf((vb).y);                     \
    _v[6] = (short)f2bf((vb).z); _v[7] = (short)f2bf((vb).w);                     \
    *reinterpret_cast<short8*>(dst) = _v; }

// lgkm-only barrier: drains LDS ops but lets global loads stay in flight
#define LBAR() { asm volatile("s_waitcnt lgkmcnt(0)" ::: "memory");               \
                 __builtin_amdgcn_s_barrier(); }

// 16 waves (4/SIMD): waves 0-7 consumers (d-eval then K-split GEMM),
// waves 8-15 producers (E8 zero + A staging, CONCURRENT with d-eval).
// GEMM reads stay at r13's optimum (320 b128/block); 2-way K-split adds a
// 16KB-scratch reduce at the end.
__global__ __launch_bounds__(1024, 4) void ssm_one(
    const float* __restrict__ u, const float* __restrict__ rho,
    const float* __restrict__ theta, const float* __restrict__ br,
    const float* __restrict__ bi, const float* __restrict__ cr,
    const float* __restrict__ ci, float* __restrict__ out) {
  __shared__ __align__(16) unsigned short Ab[2][8192];     // 32 KB A dbuf
  __shared__ __align__(16) unsigned short E8[8 * ESTR];    // 11.4 KB rev-k copies
  __shared__ __align__(16) f32x4 scr[16][64];              // 16 KB K-split reduce

  const int tid = threadIdx.x;
  const int lane = tid & 63;
  const int w = tid >> 6;                 // 0..15
  const bool prod = (w >= 8);
  const int ptid = tid & 511;             // producer-local id

  const int bid = blockIdx.x;             // 256 % 8 == 0 -> bijective XCD swizzle
  const int swz = (bid & 7) * 32 + (bid >> 3);
  const int t0 = (swz & 63) * 64;
  const int b0 = (swz >> 6) * 64;

  const int lrow = lane >> 4, lc16 = lane & 15;
  const float4 z4 = make_float4(0.f, 0.f, 0.f, 0.f);
  float4 av[2][2][2];
  f32x4 acc[2][2] = {};

#define ISSUEA(j, S) { _Pragma("unroll") for (int h_ = 0; h_ < 2; ++h_) {         \
    const int hh = ptid + 512 * h_;                                               \
    const int r_ = hh >> 4, cg = hh & 15;                                         \
    const int gg = t0 - (j) * 128 + cg * 8;                                       \
    if ((unsigned)gg < 4096u) {                                                   \
      const float* p_ = u + (size_t)(b0 + r_) * T_LEN + gg;                       \
      av[S][h_][0] = *reinterpret_cast<const float4*>(p_);                        \
      av[S][h_][1] = *reinterpret_cast<const float4*>(p_ + 4);                    \
    } else { av[S][h_][0] = z4; av[S][h_][1] = z4; } } }

#define WRITEA(buf, S) { _Pragma("unroll") for (int h_ = 0; h_ < 2; ++h_) {       \
    const int hh = ptid + 512 * h_;                                               \
    const int r_ = hh >> 4, cg = hh & 15;                                         \
    const int eo = r_ * 128 + ((cg * 8) ^ ((r_ & 7) << 3));                       \
    CVT8(&Ab[buf][eo], av[S][h_][0], av[S][h_][1]); } }

  // ---- consumer d-eval params (waves 0-7 only) ----
  float Lr[9], Li[9], gr = 0.f, gi = 0.f;
  const bool l0 = lane & 1, l1 = lane & 2, l3 = lane & 8;
  const int sig = ((lane & 1) << 2) | (lane & 2) | ((lane >> 3) & 1);
  const int cc  = ((lane >> 2) & 1) | ((lane >> 3) & 2) | ((lane >> 3) & 4);

  if (prod) {
    ISSUEA(0, 0);                         // A(0) in flight under d-eval
    const short8 z8 = {};
    for (int c = ptid; c < ESTR; c += 512)
      *reinterpret_cast<short8*>(&E8[c * 8]) = z8;
  } else {
    const float rh = rho[lane], th = theta[lane];
    const float lr2 = -1.4426950408f * log1pf(expf(rh));     // log2 r
    const float rr_ = exp2f(lr2);
    const float lre = rr_ * __cosf(th), lim = rr_ * __sinf(th);
    const float brv = br[lane], biv = bi[lane];
    const float crv = cr[lane], civ = ci[lane];
    const float wre = crv * brv + civ * biv;                 // conj(c)*b
    const float wim = crv * biv - civ * brv;
    Lr[0] = 1.f; Li[0] = 0.f;
#pragma unroll
    for (int i = 1; i <= 8; ++i) {
      Lr[i] = Lr[i - 1] * lre - Li[i - 1] * lim;
      Li[i] = Lr[i - 1] * lim + Li[i - 1] * lre;
    }
    const float d0f = (float)(8 * ROUNDS * w);               // w in 0..7
    const float rd0 = exp2f(d0f * lr2);
    float f0 = d0f * (th * 0.15915494309f);
    f0 -= floorf(f0);
    const float a0 = 6.2831853072f * f0;
    const float c0 = __cosf(a0), s0 = __sinf(a0);
    gr = rd0 * (wre * c0 - wim * s0);
    gi = rd0 * (wre * s0 + wim * c0);
  }

  LBAR();                                 // E8 zeros complete

#define ROUND(rnd) {                                                              \
    float v[8];                                                                   \
    _Pragma("unroll") for (int i2 = 0; i2 < 8; ++i2)                              \
      v[i2] = gr * Lr[i2] - gi * Li[i2];                     /* Re(g*lam^i2) */   \
    { const float ngr = gr * Lr[8] - gi * Li[8];                                  \
      const float ngi = gr * Li[8] + gi * Lr[8];                                  \
      gr = ngr; gi = ngi; }                                                       \
    float s4[4];                                                                  \
    _Pragma("unroll") for (int i = 0; i < 4; ++i) {                               \
      const float t_ = l0 ? v[i + 4] : v[i];                                      \
      const float u2 = l0 ? v[i] : v[i + 4];                                      \
      s4[i] = t_ + dppmov<0xB1>(u2); }                                            \
    float s2[2];                                                                  \
    _Pragma("unroll") for (int i = 0; i < 2; ++i) {                               \
      const float t_ = l1 ? s4[i + 2] : s4[i];                                    \
      const float u2 = l1 ? s4[i] : s4[i + 2];                                    \
      s2[i] = t_ + dppmov<0x4E>(u2); }                                            \
    float y_;                                                                     \
    { const float t_ = l3 ? s2[1] : s2[0];                                        \
      const float u2 = l3 ? s2[0] : s2[1];                                        \
      y_ = t_ + dppmov<0x128>(u2); }                                              \
    y_ += __shfl_xor(y_, 4);                                                      \
    y_ += __shfl_xor(y_, 16);                                                     \
    y_ += __shfl_xor(y_, 32);                                                     \
    const int d_ = 72 * w + 8 * (rnd) + sig;                                      \
    const int yy = CMAX - d_;                                                     \
    if (yy >= cc) E8[cc * ESTR + (yy - cc)] = f2bf(y_); }

  // ---- d-eval (consumers) CONCURRENT with A(0) staging (producers) ----
  if (prod) {
    WRITEA(0, 0);                         // waits its own vmcnt via reg use
    ISSUEA(1, 1);
  } else {
    ROUND(0); ROUND(1); ROUND(2); ROUND(3); ROUND(4);
    ROUND(5); ROUND(6); ROUND(7); ROUND(8);
  }
  LBAR();                                 // E8 + Ab[0] ready; ISSUEA(1) in flight

  const int qr = (w >> 2) & 1, qc = (w >> 1) & 1, kh = w & 1;

#define COMPUTE(jj, buf) {                                                        \
    const unsigned short* A = Ab[buf];                                            \
    const int pB = 7 - (lc16 & 7);                                                \
    _Pragma("unroll") for (int ksl = 0; ksl < 2; ++ksl) {                         \
      const int ks = kh * 2 + ksl;                                                \
      short8 af[2], bfr[2];                                                       \
      _Pragma("unroll") for (int ft = 0; ft < 2; ++ft) {                          \
        const int r = qr * 32 + ft * 16 + lc16;                                   \
        const int pe = (ks * 32 + lrow * 8) ^ ((r & 7) << 3);                     \
        af[ft] = *reinterpret_cast<const short8*>(&A[r * 128 + pe]); }            \
      _Pragma("unroll") for (int fn = 0; fn < 2; ++fn) {                          \
        const int tc = qc * 32 + fn * 16 + lc16;                                  \
        const int x0 = CMAX - (jj) * 128 - tc + ks * 32 + lrow * 8 - pB;          \
        bfr[fn] = *reinterpret_cast<const short8*>(&E8[pB * ESTR + x0]); }        \
      _Pragma("unroll") for (int ft = 0; ft < 2; ++ft)                            \
        _Pragma("unroll") for (int fn = 0; fn < 2; ++fn)                          \
          acc[ft][fn] = __builtin_amdgcn_mfma_f32_16x16x32_bf16(                  \
              af[ft], bfr[fn], acc[ft][fn], 0, 0, 0); } }

  // ---- j-pipeline (r13 schedule): producers stage, consumers compute ----
#pragma unroll
  for (int j = 0; j < NLAG; ++j) {
    if (prod) {
      if (j + 1 < NLAG) WRITEA((j + 1) & 1, (j + 1) & 1);
      if (j + 2 < NLAG) ISSUEA(j + 2, j & 1);
    } else {
      COMPUTE(j, j & 1);
    }
    if (j < NLAG - 1) LBAR();
  }

  // ---- K-split reduce: kh=1 -> scratch; kh=0 adds and stores ----
  const int qid = qr * 2 + qc;
  if (!prod && kh == 1) {
#pragma unroll
    for (int ft = 0; ft < 2; ++ft)
#pragma unroll
      for (int fn = 0; fn < 2; ++fn)
        scr[qid * 4 + ft * 2 + fn][lane] = acc[ft][fn];
  }
  LBAR();
  if (!prod && kh == 0) {
#pragma unroll
    for (int ft = 0; ft < 2; ++ft)
#pragma unroll
      for (int fn = 0; fn < 2; ++fn) {
        const f32x4 s = scr[qid * 4 + ft * 2 + fn][lane];
#pragma unroll
        for (int rg = 0; rg < 4; ++rg) {
          const int row = b0 + qr * 32 + ft * 16 + lrow * 4 + rg;
          const int col = t0 + qc * 32 + fn * 16 + lc16;
          out[(size_t)row * T_LEN + col] = acc[ft][fn][rg] + s[rg];
        }
      }
  }
#undef ISSUEA
#undef WRITEA
#undef COMPUTE
#undef ROUND
}

extern "C" void kernel_launch(void* const* d_in, const int* in_sizes, int n_in,
                              void* d_out, int out_size, void* d_ws, size_t ws_size,
                              hipStream_t stream) {
  const float* u     = (const float*)d_in[0];
  const float* rho   = (const float*)d_in[1];
  const float* theta = (const float*)d_in[2];
  const float* br    = (const float*)d_in[3];
  const float* bi    = (const float*)d_in[4];
  const float* cr    = (const float*)d_in[5];
  const float* ci    = (const float*)d_in[6];
  float* out = (float*)d_out;

  ssm_one<<<256, 1024, 0, stream>>>(u, rho, theta, br, bi, cr, ci, out);
}